// Round 5
// baseline (259.917 us; speedup 1.0000x reference)
//
#include <hip/hip_runtime.h>
#include <cstddef>

namespace {

constexpr int B = 4, V = 20000, P = 400000, NN = 50000, MP = 32;
constexpr float GAMMA = 10.0f, INV_GAMMA = 0.1f;
constexpr float KSOFT = 2.0f;
constexpr float THRESH = 1.0f;
constexpr float W_WL = 1.0f, W_CONG = 0.5f;
constexpr int BLOCKS_PER_BATCH = 256;              // phase B
constexpr int NET_GRID = BLOCKS_PER_BATCH * B;     // 1024 blocks, 4 waves
constexpr int A_SUBS = 196;                        // phase A: 196*4*64 = 50176 >= NN
constexpr int A_GRID = A_SUBS * B;                 // 784 blocks

typedef __attribute__((ext_vector_type(8)))  short bf16x8;
typedef __attribute__((ext_vector_type(16))) float f32x16;

__device__ __forceinline__ float fast_rcp(float x) { return __builtin_amdgcn_rcpf(x); }
__device__ __forceinline__ float sigmoidf(float z) { return fast_rcp(1.0f + __expf(-z)); }
__device__ __forceinline__ short f2bf(float f) {
    unsigned u = __float_as_uint(f);
    u += 0x7fffu + ((u >> 16) & 1u);
    return (short)(u >> 16);
}
template <int CTRL>
__device__ __forceinline__ float dpp_mov(float x, float id) {
    return __int_as_float(__builtin_amdgcn_update_dpp(
        __float_as_int(id), __float_as_int(x), CTRL, 0xf, 0xf, false));
}
__device__ __forceinline__ float rdlane(float x, int l) {
    return __int_as_float(__builtin_amdgcn_readlane(__float_as_int(x), l));
}
#define DPP5(x, OP, ID)                              \
    x = OP(x, dpp_mov<0x111>(x, ID));                \
    x = OP(x, dpp_mov<0x112>(x, ID));                \
    x = OP(x, dpp_mov<0x114>(x, ID));                \
    x = OP(x, dpp_mov<0x118>(x, ID));                \
    x = OP(x, dpp_mov<0x142>(x, ID));
__device__ __forceinline__ float op_add(float a, float b) { return a + b; }

__global__ void zero_ws_kernel(float* __restrict__ p, int n) {
    int i = blockIdx.x * blockDim.x + threadIdx.x;
    if (i < n) p[i] = 0.0f;
}

__global__ void macro_prep_kernel(const float* __restrict__ positions,
                                  const float* __restrict__ rot_onehot,
                                  float4* __restrict__ mac) {
    int i = blockIdx.x * blockDim.x + threadIdx.x;
    if (i >= B * V) return;
    float2 pos = ((const float2*)positions)[i];
    float4 w = ((const float4*)rot_onehot)[i];
    mac[i] = make_float4(pos.x, pos.y, w.x - w.z, w.y - w.w);
}

__global__ void pin_pos_kernel(const float4* __restrict__ mac,
                               const int* __restrict__ pin_to_macro,
                               const float* __restrict__ pin_offsets,
                               float* __restrict__ pin_pos) {
    int idx = blockIdx.x * blockDim.x + threadIdx.x;
    if (idx >= B * P) return;
    int b = idx / P;
    int p = idx - b * P;
    int m = pin_to_macro[p];
    float2 off = ((const float2*)pin_offsets)[p];
    float4 md = mac[(size_t)b * V + m];
    ((float2*)pin_pos)[idx] = make_float2(md.x + md.z * off.x - md.w * off.y,
                                          md.y + md.w * off.x + md.z * off.y);
}

// n2pT[j][n] = n2p[n][j]  (coalesced phase-A index loads)
__global__ void transpose_n2p_kernel(const int* __restrict__ n2p,
                                     int* __restrict__ n2pT) {
    int i = blockIdx.x * blockDim.x + threadIdx.x;
    if (i >= NN * MP) return;
    int n = i >> 5, j = i & 31;
    n2pT[j * NN + n] = n2p[i];
}

// Phase A: ONE NET PER LANE. No cross-lane ops in the pin loop -> full MLP.
// Outputs: bbox[b*NN+n] = grid-space (xmin,xmax,ymin,ymax); hpwl[b] (atomic).
__global__ void __launch_bounds__(256)
bbox_kernel(const float* __restrict__ pin_pos,
            const int* __restrict__ n2pT,
            const float* __restrict__ net_weights,
            float4* __restrict__ bbox,
            float* __restrict__ hpwl) {
    __shared__ float hps[4];
    int blk = blockIdx.x;
    int xcd = blk & 7;
    int b = xcd >> 1;                         // batch -> XCD pair
    int sub = ((blk >> 3) << 1) | (xcd & 1);  // 0..A_SUBS-1
    int tid = threadIdx.x;
    int wave = tid >> 6;
    int lane = tid & 63;

    int n = sub * 256 + wave * 64 + lane;
    bool inrange = n < NN;
    int nc = inrange ? n : (NN - 1);

    const float2* pp = (const float2*)(pin_pos + (size_t)b * P * 2);

    // batch all 32 index loads up front (coalesced via transpose)
    int pi[MP];
    #pragma unroll
    for (int j = 0; j < MP; ++j) pi[j] = n2pT[j * NN + nc];

    float ex1 = 0.f, ex2 = 0.f, ey1 = 0.f, ey2 = 0.f;
    float vxmax = -1e30f, vxmin = 1e30f, vymax = -1e30f, vymin = 1e30f;
    #pragma unroll 8
    for (int j = 0; j < MP; ++j) {
        bool v = pi[j] >= 0;
        float2 q = pp[v ? pi[j] : 0];         // address uncond -> loads batch per unroll chunk
        float e1x = __expf(GAMMA * q.x);
        float e1y = __expf(GAMMA * q.y);
        ex1 += v ? e1x : 0.f;
        ex2 += v ? fast_rcp(e1x) : 0.f;       // e^{-gx} = 1/e^{gx}; |gx|<=10.4, fp32-safe
        ey1 += v ? e1y : 0.f;
        ey2 += v ? fast_rcp(e1y) : 0.f;
        vxmax = fmaxf(vxmax, v ? q.x : -1e30f);
        vxmin = fminf(vxmin, v ? q.x :  1e30f);
        vymax = fmaxf(vymax, v ? q.y : -1e30f);
        vymin = fminf(vymin, v ? q.y :  1e30f);
    }
    float w = net_weights[nc];
    float wl = __logf(ex1 * ex2 * ey1 * ey2) * INV_GAMMA;
    float hp = inrange ? wl * w : 0.f;

    if (inrange) {
        bbox[(size_t)b * NN + n] = make_float4(
            (vxmin + 1.0f) * 31.5f, (vxmax + 1.0f) * 31.5f,
            (vymin + 1.0f) * 31.5f, (vymax + 1.0f) * 31.5f);
    }
    // block-level hpwl reduction -> one atomic per block
    DPP5(hp, op_add, 0.0f);
    float tot = rdlane(hp, 31) + rdlane(hp, 63);
    if (lane == 0) hps[wave] = tot;
    __syncthreads();
    if (tid == 0) atomicAdd(&hpwl[b], hps[0] + hps[1] + hps[2] + hps[3]);
}

// Phase B: wave-uniform bbox reads (scalar loads), sigmoid profiles, rank-16 MFMA.
__global__ void __launch_bounds__(256)
rudy_kernel(const float4* __restrict__ bbox,
            float* __restrict__ rudy) {   // B * 64 * 64
    __shared__ float tile[64 * 65];
    int x = blockIdx.x;
    int xcd = x & 7;
    int b = xcd >> 1;
    int sub = ((x >> 3) << 1) | (xcd & 1);
    int tid = threadIdx.x;
    int lane = tid & 63;
    bool lo = lane < 32;
    float g = (float)lane;

    for (int k = tid; k < 64 * 65; k += 256) tile[k] = 0.0f;
    __syncthreads();

    f32x16 acc00, acc01, acc10, acc11;
    #pragma unroll
    for (int r = 0; r < 16; ++r) { acc00[r] = 0.f; acc01[r] = 0.f; acc10[r] = 0.f; acc11[r] = 0.f; }

    const int wstride = BLOCKS_PER_BATCH * 4;
    int n0 = __builtin_amdgcn_readfirstlane(sub * 4 + (tid >> 6));  // force uniform
    const float4* bb_b = bbox + (size_t)b * NN;

    for (int grp = 0; grp < 4; ++grp) {
        bf16x8 A0, A1, B0, B1;
        float xlo[8], ylo[8];
        #pragma unroll
        for (int t = 0; t < 16; ++t) {
            int nt = n0 + (grp * 16 + t) * wstride;   // uniform
            float xv = 0.f, yv = 0.f;
            if (nt < NN) {
                float4 bb = bb_b[nt];                  // scalar load
                float inv_size = fast_rcp(
                    fmaxf((bb.y - bb.x + 1.0f) * (bb.w - bb.z + 1.0f), 1.0f));
                xv = sigmoidf(KSOFT * (g - bb.x + 0.5f)) * sigmoidf(KSOFT * (bb.y - g + 0.5f));
                yv = sigmoidf(KSOFT * (g - bb.z + 0.5f)) * sigmoidf(KSOFT * (bb.w - g + 0.5f))
                   * inv_size;
            }
            if (t < 8) { xlo[t] = xv; ylo[t] = yv; }
            else {
                int j = t - 8;  // constant under unroll
                float syl = __shfl_xor(ylo[j], 32, 64), sxl = __shfl_xor(xlo[j], 32, 64);
                float syh = __shfl_xor(yv, 32, 64),     sxh = __shfl_xor(xv, 32, 64);
                A0[j] = f2bf(lo ? ylo[j] : syh);   // rows 0-31   (A = Y^T)
                A1[j] = f2bf(lo ? syl : yv);       // rows 32-63
                B0[j] = f2bf(lo ? xlo[j] : sxh);   // cols 0-31   (B = X)
                B1[j] = f2bf(lo ? sxl : xv);       // cols 32-63
            }
        }
        acc00 = __builtin_amdgcn_mfma_f32_32x32x16_bf16(A0, B0, acc00, 0, 0, 0);
        acc01 = __builtin_amdgcn_mfma_f32_32x32x16_bf16(A0, B1, acc01, 0, 0, 0);
        acc10 = __builtin_amdgcn_mfma_f32_32x32x16_bf16(A1, B0, acc10, 0, 0, 0);
        acc11 = __builtin_amdgcn_mfma_f32_32x32x16_bf16(A1, B1, acc11, 0, 0, 0);
    }

    // C/D layout: col=lane&31, row=(r&3)+8*(r>>2)+4*(lane>>5)
    int col = lane & 31, rq = lane >> 5;
    #pragma unroll
    for (int r = 0; r < 16; ++r) {
        int row = (r & 3) + 8 * (r >> 2) + 4 * rq;
        atomicAdd(&tile[row * 65 + col],             acc00[r]);
        atomicAdd(&tile[row * 65 + col + 32],        acc01[r]);
        atomicAdd(&tile[(row + 32) * 65 + col],      acc10[r]);
        atomicAdd(&tile[(row + 32) * 65 + col + 32], acc11[r]);
    }
    __syncthreads();
    for (int k = tid; k < 4096; k += 256) {
        int i = k >> 6, j = k & 63;
        atomicAdd(&rudy[(size_t)b * 4096 + k], tile[i * 65 + j]);
    }
}

// 64 blocks: (batch, 4-row chunk). Was 4 blocks = 4 CUs.
__global__ void conv_penalty_kernel(const float* __restrict__ rudy,
                                    float* __restrict__ pen) {
    int blk = blockIdx.x;
    int b = blk >> 4, chunk = blk & 15;
    int r0 = chunk * 4;
    __shared__ float t2[10][64];
    int tid = threadIdx.x;
    for (int k = tid; k < 640; k += 256) {
        int r = k >> 6, c = k & 63, row = r0 - 3 + r;
        t2[r][c] = (row >= 0 && row < 64) ? rudy[b * 4096 + row * 64 + c] : 0.f;
    }
    __syncthreads();
    float g1[7];
    #pragma unroll
    for (int i = 0; i < 7; ++i) { float t = (float)(i - 3); g1[i] = __expf(-t * t / 4.5f); }
    float s1 = g1[0] + g1[1] + g1[2] + g1[3] + g1[4] + g1[5] + g1[6];
    float inv = fast_rcp(s1 * s1);
    int i = tid >> 6, j = tid & 63;   // each thread owns one cell
    float acc = 0.f;
    #pragma unroll
    for (int di = -3; di <= 3; ++di) {
        #pragma unroll
        for (int dj = -3; dj <= 3; ++dj) {
            int jj = j + dj;
            float val = (jj >= 0 && jj < 64) ? t2[i + 3 + di][jj] : 0.f;
            acc += g1[di + 3] * g1[dj + 3] * val;
        }
    }
    acc *= inv;
    float ov = acc - THRESH;
    float p = ov > 0.f ? ov * ov : 0.f;
    DPP5(p, op_add, 0.0f);
    float tot = rdlane(p, 31) + rdlane(p, 63);
    if ((tid & 63) == 0) atomicAdd(&pen[b], tot);
}

__global__ void finalize_kernel(const float* __restrict__ hpwl,
                                const float* __restrict__ pen,
                                float* __restrict__ out) {
    int i = threadIdx.x;
    if (i < B) out[i] = W_WL * hpwl[i] + W_CONG * pen[i];
}

} // namespace

extern "C" void kernel_launch(void* const* d_in, const int* in_sizes, int n_in,
                              void* d_out, int out_size, void* d_ws, size_t ws_size,
                              hipStream_t stream) {
    const float* positions    = (const float*)d_in[0];
    const int*   net_to_pin   = (const int*)d_in[1];
    const int*   pin_to_macro = (const int*)d_in[2];
    const float* pin_offsets  = (const float*)d_in[3];
    const float* rot_onehot   = (const float*)d_in[4];
    const float* net_weights  = (const float*)d_in[5];
    float* out = (float*)d_out;

    // ws: pin_pos | rudy | hpwl | pen | mac | bbox | n2pT   (~24 MB)
    float*  pin_pos = (float*)d_ws;
    float*  rudy    = pin_pos + (size_t)B * P * 2;        // 3,200,000
    float*  hpwl    = rudy + (size_t)B * 64 * 64;         // +16384
    float*  pen     = hpwl + B;                            // +4
    float4* mac     = (float4*)(pen + B);                  // 16B-aligned (offset 12,865,568 B)
    float4* bboxb   = mac + (size_t)B * V;
    int*    n2pT    = (int*)(bboxb + (size_t)B * NN);

    int nz = B * 4096 + 2 * B;   // rudy + hpwl + pen contiguous
    zero_ws_kernel<<<(nz + 255) / 256, 256, 0, stream>>>(rudy, nz);
    macro_prep_kernel<<<(B * V + 255) / 256, 256, 0, stream>>>(positions, rot_onehot, mac);
    pin_pos_kernel<<<(B * P + 255) / 256, 256, 0, stream>>>(mac, pin_to_macro, pin_offsets, pin_pos);
    transpose_n2p_kernel<<<(NN * MP + 255) / 256, 256, 0, stream>>>(net_to_pin, n2pT);
    bbox_kernel<<<A_GRID, 256, 0, stream>>>(pin_pos, n2pT, net_weights, bboxb, hpwl);
    rudy_kernel<<<NET_GRID, 256, 0, stream>>>(bboxb, rudy);
    conv_penalty_kernel<<<64, 256, 0, stream>>>(rudy, pen);
    finalize_kernel<<<1, 64, 0, stream>>>(hpwl, pen, out);
}

// Round 6
// 218.784 us; speedup vs baseline: 1.1880x; 1.1880x over previous
//
#include <hip/hip_runtime.h>
#include <cstddef>

namespace {

constexpr int B = 4, V = 20000, P = 400000, NN = 50000, MP = 32;
constexpr float GAMMA = 10.0f, INV_GAMMA = 0.1f;
constexpr float KSOFT = 2.0f;
constexpr float THRESH = 1.0f;
constexpr float W_WL = 1.0f, W_CONG = 0.5f;
constexpr int BPB = 128;                   // phase-B blocks per batch
constexpr int NET_GRID = BPB * B;          // 512 blocks, 4 waves
constexpr int GRPS = 7;                    // 7*16*512 = 57344 >= NN per wave-stream
constexpr int A_SUBS = 196;                // phase A: 196*256 = 50176 >= NN
constexpr int A_GRID = A_SUBS * B;

typedef __attribute__((ext_vector_type(8)))  short bf16x8;
typedef __attribute__((ext_vector_type(16))) float f32x16;

__device__ __forceinline__ float fast_rcp(float x) { return __builtin_amdgcn_rcpf(x); }
__device__ __forceinline__ float sigmoidf(float z) { return fast_rcp(1.0f + __expf(-z)); }
__device__ __forceinline__ short f2bf(float f) {
    unsigned u = __float_as_uint(f);
    u += 0x7fffu + ((u >> 16) & 1u);
    return (short)(u >> 16);
}
template <int CTRL>
__device__ __forceinline__ float dpp_mov(float x, float id) {
    return __int_as_float(__builtin_amdgcn_update_dpp(
        __float_as_int(id), __float_as_int(x), CTRL, 0xf, 0xf, false));
}
__device__ __forceinline__ float rdlane(float x, int l) {
    return __int_as_float(__builtin_amdgcn_readlane(__float_as_int(x), l));
}
#define DPP5(x, OP, ID)                              \
    x = OP(x, dpp_mov<0x111>(x, ID));                \
    x = OP(x, dpp_mov<0x112>(x, ID));                \
    x = OP(x, dpp_mov<0x114>(x, ID));                \
    x = OP(x, dpp_mov<0x118>(x, ID));                \
    x = OP(x, dpp_mov<0x142>(x, ID));
__device__ __forceinline__ float op_add(float a, float b) { return a + b; }

__global__ void zero_ws_kernel(float* __restrict__ p, int n) {
    int i = blockIdx.x * blockDim.x + threadIdx.x;
    if (i < n) p[i] = 0.0f;
}

__global__ void macro_prep_kernel(const float* __restrict__ positions,
                                  const float* __restrict__ rot_onehot,
                                  float4* __restrict__ mac) {
    int i = blockIdx.x * blockDim.x + threadIdx.x;
    if (i >= B * V) return;
    float2 pos = ((const float2*)positions)[i];
    float4 w = ((const float4*)rot_onehot)[i];
    mac[i] = make_float4(pos.x, pos.y, w.x - w.z, w.y - w.w);
}

__global__ void pin_pos_kernel(const float4* __restrict__ mac,
                               const int* __restrict__ pin_to_macro,
                               const float* __restrict__ pin_offsets,
                               float* __restrict__ pin_pos) {
    int idx = blockIdx.x * blockDim.x + threadIdx.x;
    if (idx >= B * P) return;
    int b = idx / P;
    int p = idx - b * P;
    int m = pin_to_macro[p];
    float2 off = ((const float2*)pin_offsets)[p];
    float4 md = mac[(size_t)b * V + m];
    ((float2*)pin_pos)[idx] = make_float2(md.x + md.z * off.x - md.w * off.y,
                                          md.y + md.w * off.x + md.z * off.y);
}

__global__ void transpose_n2p_kernel(const int* __restrict__ n2p,
                                     int* __restrict__ n2pT) {
    int i = blockIdx.x * blockDim.x + threadIdx.x;
    if (i >= NN * MP) return;
    int n = i >> 5, j = i & 31;
    n2pT[j * NN + n] = n2p[i];
}

// Phase A: one net per LANE; no cross-lane ops in the pin loop (full MLP).
__global__ void __launch_bounds__(256)
bbox_kernel(const float* __restrict__ pin_pos,
            const int* __restrict__ n2pT,
            const float* __restrict__ net_weights,
            float4* __restrict__ bbox,
            float* __restrict__ hpwl) {
    __shared__ float hps[4];
    int blk = blockIdx.x;
    int xcd = blk & 7;
    int b = xcd >> 1;
    int sub = ((blk >> 3) << 1) | (xcd & 1);
    int tid = threadIdx.x;
    int wave = tid >> 6;
    int lane = tid & 63;

    int n = sub * 256 + wave * 64 + lane;
    bool inrange = n < NN;
    int nc = inrange ? n : (NN - 1);

    const float2* pp = (const float2*)(pin_pos + (size_t)b * P * 2);

    int pi[MP];
    #pragma unroll
    for (int j = 0; j < MP; ++j) pi[j] = n2pT[j * NN + nc];

    float ex1 = 0.f, ex2 = 0.f, ey1 = 0.f, ey2 = 0.f;
    float vxmax = -1e30f, vxmin = 1e30f, vymax = -1e30f, vymin = 1e30f;
    #pragma unroll 8
    for (int j = 0; j < MP; ++j) {
        bool v = pi[j] >= 0;
        float2 q = pp[v ? pi[j] : 0];
        float e1x = __expf(GAMMA * q.x);
        float e1y = __expf(GAMMA * q.y);
        ex1 += v ? e1x : 0.f;
        ex2 += v ? fast_rcp(e1x) : 0.f;
        ey1 += v ? e1y : 0.f;
        ey2 += v ? fast_rcp(e1y) : 0.f;
        vxmax = fmaxf(vxmax, v ? q.x : -1e30f);
        vxmin = fminf(vxmin, v ? q.x :  1e30f);
        vymax = fmaxf(vymax, v ? q.y : -1e30f);
        vymin = fminf(vymin, v ? q.y :  1e30f);
    }
    float w = net_weights[nc];
    float wl = __logf(ex1 * ex2 * ey1 * ey2) * INV_GAMMA;
    float hp = inrange ? wl * w : 0.f;

    if (inrange) {
        bbox[(size_t)b * NN + n] = make_float4(
            (vxmin + 1.0f) * 31.5f, (vxmax + 1.0f) * 31.5f,
            (vymin + 1.0f) * 31.5f, (vymax + 1.0f) * 31.5f);
    }
    DPP5(hp, op_add, 0.0f);
    float tot = rdlane(hp, 31) + rdlane(hp, 63);
    if (lane == 0) hps[wave] = tot;
    __syncthreads();
    if (tid == 0) atomicAdd(&hpwl[b], hps[0] + hps[1] + hps[2] + hps[3]);
}

// Phase B: batched wave-uniform bbox loads, sigmoid profiles, rank-16 MFMA.
// Epilogue: PLAIN STORES to a private slab (no global atomics — they were a
// 130 us memory-side-serialization floor: 4.2M device atomics = 16.4MB WRITE_SIZE).
__global__ void __launch_bounds__(256)
rudy_kernel(const float4* __restrict__ bbox,
            float* __restrict__ slabs) {   // NET_GRID * 4096
    __shared__ float tile[64 * 65];
    int x = blockIdx.x;
    int xcd = x & 7;
    int b = xcd >> 1;
    int sub = ((x >> 3) << 1) | (xcd & 1);     // 0..BPB-1
    int tid = threadIdx.x;
    int lane = tid & 63;
    bool lo = lane < 32;
    float g = (float)lane;

    for (int k = tid; k < 64 * 65; k += 256) tile[k] = 0.0f;
    __syncthreads();

    f32x16 acc00, acc01, acc10, acc11;
    #pragma unroll
    for (int r = 0; r < 16; ++r) { acc00[r] = 0.f; acc01[r] = 0.f; acc10[r] = 0.f; acc11[r] = 0.f; }

    const int wstride = BPB * 4;               // 512
    int n0 = __builtin_amdgcn_readfirstlane(sub * 4 + (tid >> 6));
    const float4* bb_b = bbox + (size_t)b * NN;

    for (int grp = 0; grp < GRPS; ++grp) {
        bf16x8 A0, A1, B0, B1;
        float xlo[8], ylo[8];
        // ---- half 1: prefetch 8 uniform loads, then compute ----
        float4 bbv[8];
        #pragma unroll
        for (int t = 0; t < 8; ++t) {
            int nt = n0 + (grp * 16 + t) * wstride;
            bbv[t] = bb_b[nt < NN ? nt : 0];
        }
        #pragma unroll
        for (int t = 0; t < 8; ++t) {
            int nt = n0 + (grp * 16 + t) * wstride;
            float4 bb = bbv[t];
            float xv = 0.f, yv = 0.f;
            if (nt < NN) {
                float inv_size = fast_rcp(
                    fmaxf((bb.y - bb.x + 1.0f) * (bb.w - bb.z + 1.0f), 1.0f));
                xv = sigmoidf(KSOFT * (g - bb.x + 0.5f)) * sigmoidf(KSOFT * (bb.y - g + 0.5f));
                yv = sigmoidf(KSOFT * (g - bb.z + 0.5f)) * sigmoidf(KSOFT * (bb.w - g + 0.5f))
                   * inv_size;
            }
            xlo[t] = xv; ylo[t] = yv;
        }
        // ---- half 2: prefetch, compute, pair into fragments ----
        #pragma unroll
        for (int t = 0; t < 8; ++t) {
            int nt = n0 + (grp * 16 + 8 + t) * wstride;
            bbv[t] = bb_b[nt < NN ? nt : 0];
        }
        #pragma unroll
        for (int j = 0; j < 8; ++j) {
            int nt = n0 + (grp * 16 + 8 + j) * wstride;
            float4 bb = bbv[j];
            float xv = 0.f, yv = 0.f;
            if (nt < NN) {
                float inv_size = fast_rcp(
                    fmaxf((bb.y - bb.x + 1.0f) * (bb.w - bb.z + 1.0f), 1.0f));
                xv = sigmoidf(KSOFT * (g - bb.x + 0.5f)) * sigmoidf(KSOFT * (bb.y - g + 0.5f));
                yv = sigmoidf(KSOFT * (g - bb.z + 0.5f)) * sigmoidf(KSOFT * (bb.w - g + 0.5f))
                   * inv_size;
            }
            float syl = __shfl_xor(ylo[j], 32, 64), sxl = __shfl_xor(xlo[j], 32, 64);
            float syh = __shfl_xor(yv, 32, 64),     sxh = __shfl_xor(xv, 32, 64);
            A0[j] = f2bf(lo ? ylo[j] : syh);   // rows 0-31   (A = Y^T)
            A1[j] = f2bf(lo ? syl : yv);       // rows 32-63
            B0[j] = f2bf(lo ? xlo[j] : sxh);   // cols 0-31   (B = X)
            B1[j] = f2bf(lo ? sxl : xv);       // cols 32-63
        }
        acc00 = __builtin_amdgcn_mfma_f32_32x32x16_bf16(A0, B0, acc00, 0, 0, 0);
        acc01 = __builtin_amdgcn_mfma_f32_32x32x16_bf16(A0, B1, acc01, 0, 0, 0);
        acc10 = __builtin_amdgcn_mfma_f32_32x32x16_bf16(A1, B0, acc10, 0, 0, 0);
        acc11 = __builtin_amdgcn_mfma_f32_32x32x16_bf16(A1, B1, acc11, 0, 0, 0);
    }

    // C/D layout: col=lane&31, row=(r&3)+8*(r>>2)+4*(lane>>5)  (LDS atomics: intra-block, cheap)
    int col = lane & 31, rq = lane >> 5;
    #pragma unroll
    for (int r = 0; r < 16; ++r) {
        int row = (r & 3) + 8 * (r >> 2) + 4 * rq;
        atomicAdd(&tile[row * 65 + col],             acc00[r]);
        atomicAdd(&tile[row * 65 + col + 32],        acc01[r]);
        atomicAdd(&tile[(row + 32) * 65 + col],      acc10[r]);
        atomicAdd(&tile[(row + 32) * 65 + col + 32], acc11[r]);
    }
    __syncthreads();
    float* slab = slabs + ((size_t)b * BPB + sub) * 4096;
    for (int k = tid; k < 4096; k += 256)
        slab[k] = tile[(k >> 6) * 65 + (k & 63)];
}

// Sum BPB slabs -> rudy. XCD-pinned to the pair that wrote the slabs (L2 hits).
__global__ void __launch_bounds__(256)
rudy_reduce_kernel(const float* __restrict__ slabs, float* __restrict__ rudy) {
    int blk = blockIdx.x;                       // 64
    int xcd = blk & 7;
    int b = xcd >> 1;
    int sub = ((blk >> 3) << 1) | (xcd & 1);    // 0..15
    int c = sub * 256 + threadIdx.x;            // cell 0..4095
    const float* base = slabs + (size_t)b * BPB * 4096 + c;
    float a0 = 0.f, a1 = 0.f, a2 = 0.f, a3 = 0.f;
    #pragma unroll 4
    for (int s = 0; s < BPB; s += 4) {
        a0 += base[(size_t)(s + 0) * 4096];
        a1 += base[(size_t)(s + 1) * 4096];
        a2 += base[(size_t)(s + 2) * 4096];
        a3 += base[(size_t)(s + 3) * 4096];
    }
    rudy[b * 4096 + c] = (a0 + a1) + (a2 + a3);
}

__global__ void conv_penalty_kernel(const float* __restrict__ rudy,
                                    float* __restrict__ pen) {
    int blk = blockIdx.x;
    int b = blk >> 4, chunk = blk & 15;
    int r0 = chunk * 4;
    __shared__ float t2[10][64];
    int tid = threadIdx.x;
    for (int k = tid; k < 640; k += 256) {
        int r = k >> 6, c = k & 63, row = r0 - 3 + r;
        t2[r][c] = (row >= 0 && row < 64) ? rudy[b * 4096 + row * 64 + c] : 0.f;
    }
    __syncthreads();
    float g1[7];
    #pragma unroll
    for (int i = 0; i < 7; ++i) { float t = (float)(i - 3); g1[i] = __expf(-t * t / 4.5f); }
    float s1 = g1[0] + g1[1] + g1[2] + g1[3] + g1[4] + g1[5] + g1[6];
    float inv = fast_rcp(s1 * s1);
    int i = tid >> 6, j = tid & 63;
    float acc = 0.f;
    #pragma unroll
    for (int di = -3; di <= 3; ++di) {
        #pragma unroll
        for (int dj = -3; dj <= 3; ++dj) {
            int jj = j + dj;
            float val = (jj >= 0 && jj < 64) ? t2[i + 3 + di][jj] : 0.f;
            acc += g1[di + 3] * g1[dj + 3] * val;
        }
    }
    acc *= inv;
    float ov = acc - THRESH;
    float p = ov > 0.f ? ov * ov : 0.f;
    DPP5(p, op_add, 0.0f);
    float tot = rdlane(p, 31) + rdlane(p, 63);
    if ((tid & 63) == 0) atomicAdd(&pen[b], tot);
}

__global__ void finalize_kernel(const float* __restrict__ hpwl,
                                const float* __restrict__ pen,
                                float* __restrict__ out) {
    int i = threadIdx.x;
    if (i < B) out[i] = W_WL * hpwl[i] + W_CONG * pen[i];
}

} // namespace

extern "C" void kernel_launch(void* const* d_in, const int* in_sizes, int n_in,
                              void* d_out, int out_size, void* d_ws, size_t ws_size,
                              hipStream_t stream) {
    const float* positions    = (const float*)d_in[0];
    const int*   net_to_pin   = (const int*)d_in[1];
    const int*   pin_to_macro = (const int*)d_in[2];
    const float* pin_offsets  = (const float*)d_in[3];
    const float* rot_onehot   = (const float*)d_in[4];
    const float* net_weights  = (const float*)d_in[5];
    float* out = (float*)d_out;

    // ws: pin_pos | rudy | hpwl | pen | mac | bbox | n2pT | slabs  (~32 MB)
    float*  pin_pos = (float*)d_ws;
    float*  rudy    = pin_pos + (size_t)B * P * 2;        // 3,200,000
    float*  hpwl    = rudy + (size_t)B * 64 * 64;
    float*  pen     = hpwl + B;
    float4* mac     = (float4*)(pen + B);                  // 16B-aligned
    float4* bboxb   = mac + (size_t)B * V;
    int*    n2pT    = (int*)(bboxb + (size_t)B * NN);
    float*  slabs   = (float*)(n2pT + (size_t)NN * MP);    // NET_GRID*4096 = 8.4 MB

    zero_ws_kernel<<<1, 64, 0, stream>>>(hpwl, 2 * B);     // hpwl + pen only
    macro_prep_kernel<<<(B * V + 255) / 256, 256, 0, stream>>>(positions, rot_onehot, mac);
    pin_pos_kernel<<<(B * P + 255) / 256, 256, 0, stream>>>(mac, pin_to_macro, pin_offsets, pin_pos);
    transpose_n2p_kernel<<<(NN * MP + 255) / 256, 256, 0, stream>>>(net_to_pin, n2pT);
    bbox_kernel<<<A_GRID, 256, 0, stream>>>(pin_pos, n2pT, net_weights, bboxb, hpwl);
    rudy_kernel<<<NET_GRID, 256, 0, stream>>>(bboxb, slabs);
    rudy_reduce_kernel<<<64, 256, 0, stream>>>(slabs, rudy);
    conv_penalty_kernel<<<64, 256, 0, stream>>>(rudy, pen);
    finalize_kernel<<<1, 64, 0, stream>>>(hpwl, pen, out);
}

// Round 7
// 199.641 us; speedup vs baseline: 1.3019x; 1.0959x over previous
//
#include <hip/hip_runtime.h>
#include <cstddef>

namespace {

constexpr int B = 4, V = 20000, P = 400000, NN = 50000, MP = 32;
constexpr float GAMMA = 10.0f, INV_GAMMA = 0.1f;
constexpr float KSOFT = 2.0f;
constexpr float THRESH = 1.0f;
constexpr float W_WL = 1.0f, W_CONG = 0.5f;
constexpr int BPB = 128;                   // phase-B blocks per batch
constexpr int NET_GRID = BPB * B;          // 512 blocks, 4 waves
constexpr int GRPS = 7;                    // 112 contiguous nets per wave-stream
constexpr int NPW = GRPS * 16;             // 112
constexpr int A_SUBS = 196;                // phase A: 196*256 = 50176 >= NN
constexpr int A_GRID = A_SUBS * B;

typedef __attribute__((ext_vector_type(8)))  short bf16x8;
typedef __attribute__((ext_vector_type(16))) float f32x16;

__device__ __forceinline__ float fast_rcp(float x) { return __builtin_amdgcn_rcpf(x); }
__device__ __forceinline__ float sigmoidf(float z) { return fast_rcp(1.0f + __expf(-z)); }
__device__ __forceinline__ short f2bf(float f) {
    unsigned u = __float_as_uint(f);
    u += 0x7fffu + ((u >> 16) & 1u);
    return (short)(u >> 16);
}
template <int CTRL>
__device__ __forceinline__ float dpp_mov(float x, float id) {
    return __int_as_float(__builtin_amdgcn_update_dpp(
        __float_as_int(id), __float_as_int(x), CTRL, 0xf, 0xf, false));
}
__device__ __forceinline__ float rdlane(float x, int l) {
    return __int_as_float(__builtin_amdgcn_readlane(__float_as_int(x), l));
}
#define DPP5(x, OP, ID)                              \
    x = OP(x, dpp_mov<0x111>(x, ID));                \
    x = OP(x, dpp_mov<0x112>(x, ID));                \
    x = OP(x, dpp_mov<0x114>(x, ID));                \
    x = OP(x, dpp_mov<0x118>(x, ID));                \
    x = OP(x, dpp_mov<0x142>(x, ID));
__device__ __forceinline__ float op_add(float a, float b) { return a + b; }

__global__ void zero_ws_kernel(float* __restrict__ p, int n) {
    int i = blockIdx.x * blockDim.x + threadIdx.x;
    if (i < n) p[i] = 0.0f;
}

__global__ void macro_prep_kernel(const float* __restrict__ positions,
                                  const float* __restrict__ rot_onehot,
                                  float4* __restrict__ mac) {
    int i = blockIdx.x * blockDim.x + threadIdx.x;
    if (i >= B * V) return;
    float2 pos = ((const float2*)positions)[i];
    float4 w = ((const float4*)rot_onehot)[i];
    mac[i] = make_float4(pos.x, pos.y, w.x - w.z, w.y - w.w);
}

__global__ void pin_pos_kernel(const float4* __restrict__ mac,
                               const int* __restrict__ pin_to_macro,
                               const float* __restrict__ pin_offsets,
                               float* __restrict__ pin_pos) {
    int idx = blockIdx.x * blockDim.x + threadIdx.x;
    if (idx >= B * P) return;
    int b = idx / P;
    int p = idx - b * P;
    int m = pin_to_macro[p];
    float2 off = ((const float2*)pin_offsets)[p];
    float4 md = mac[(size_t)b * V + m];
    ((float2*)pin_pos)[idx] = make_float2(md.x + md.z * off.x - md.w * off.y,
                                          md.y + md.w * off.x + md.z * off.y);
}

__global__ void transpose_n2p_kernel(const int* __restrict__ n2p,
                                     int* __restrict__ n2pT) {
    int i = blockIdx.x * blockDim.x + threadIdx.x;
    if (i >= NN * MP) return;
    int n = i >> 5, j = i & 31;
    n2pT[j * NN + n] = n2p[i];
}

// Phase A: one net per LANE; no cross-lane ops in the pin loop (full MLP).
__global__ void __launch_bounds__(256)
bbox_kernel(const float* __restrict__ pin_pos,
            const int* __restrict__ n2pT,
            const float* __restrict__ net_weights,
            float4* __restrict__ bbox,
            float* __restrict__ hpwl) {
    __shared__ float hps[4];
    int blk = blockIdx.x;
    int xcd = blk & 7;
    int b = xcd >> 1;
    int sub = ((blk >> 3) << 1) | (xcd & 1);
    int tid = threadIdx.x;
    int wave = tid >> 6;
    int lane = tid & 63;

    int n = sub * 256 + wave * 64 + lane;
    bool inrange = n < NN;
    int nc = inrange ? n : (NN - 1);

    const float2* pp = (const float2*)(pin_pos + (size_t)b * P * 2);

    int pi[MP];
    #pragma unroll
    for (int j = 0; j < MP; ++j) pi[j] = n2pT[j * NN + nc];

    float ex1 = 0.f, ex2 = 0.f, ey1 = 0.f, ey2 = 0.f;
    float vxmax = -1e30f, vxmin = 1e30f, vymax = -1e30f, vymin = 1e30f;
    #pragma unroll 8
    for (int j = 0; j < MP; ++j) {
        bool v = pi[j] >= 0;
        float2 q = pp[v ? pi[j] : 0];
        float e1x = __expf(GAMMA * q.x);
        float e1y = __expf(GAMMA * q.y);
        ex1 += v ? e1x : 0.f;
        ex2 += v ? fast_rcp(e1x) : 0.f;
        ey1 += v ? e1y : 0.f;
        ey2 += v ? fast_rcp(e1y) : 0.f;
        vxmax = fmaxf(vxmax, v ? q.x : -1e30f);
        vxmin = fminf(vxmin, v ? q.x :  1e30f);
        vymax = fmaxf(vymax, v ? q.y : -1e30f);
        vymin = fminf(vymin, v ? q.y :  1e30f);
    }
    float w = net_weights[nc];
    float wl = __logf(ex1 * ex2 * ey1 * ey2) * INV_GAMMA;
    float hp = inrange ? wl * w : 0.f;

    if (inrange) {
        bbox[(size_t)b * NN + n] = make_float4(
            (vxmin + 1.0f) * 31.5f, (vxmax + 1.0f) * 31.5f,
            (vymin + 1.0f) * 31.5f, (vymax + 1.0f) * 31.5f);
    }
    DPP5(hp, op_add, 0.0f);
    float tot = rdlane(hp, 31) + rdlane(hp, 63);
    if (lane == 0) hps[wave] = tot;
    __syncthreads();
    if (tid == 0) atomicAdd(&hpwl[b], hps[0] + hps[1] + hps[2] + hps[3]);
}

// Phase B: CONTIGUOUS 112-net stream per wave. Each lane computes its MFMA
// fragment elements DIRECTLY (per-lane VMEM bbox loads, broadcast within
// half-wave; zero cross-lane ops, zero scalar loads — R6 was serialized on
// s_load/ds_bpermute sharing lgkmcnt). Rank-16 MFMA onto the matrix pipe.
__global__ void __launch_bounds__(256)
rudy_kernel(const float4* __restrict__ bbox,
            float* __restrict__ slabs) {   // NET_GRID * 4096
    __shared__ float tile[64 * 65];
    int x = blockIdx.x;
    int xcd = x & 7;
    int b = xcd >> 1;
    int sub = ((x >> 3) << 1) | (xcd & 1);     // 0..BPB-1
    int tid = threadIdx.x;
    int wave = tid >> 6;
    int lane = tid & 63;

    for (int k = tid; k < 64 * 65; k += 256) tile[k] = 0.0f;
    __syncthreads();

    f32x16 acc00, acc01, acc10, acc11;
    #pragma unroll
    for (int r = 0; r < 16; ++r) { acc00[r] = 0.f; acc01[r] = 0.f; acc10[r] = 0.f; acc11[r] = 0.f; }

    int s = sub * 4 + wave;                    // wave-stream id, 0..511
    int s0 = s * NPW;                          // first net of this stream
    const float4* bb_b = bbox + (size_t)b * NN;

    int half8 = (lane >> 5) * 8;               // k-slot base for this half-wave
    float g2 = (float)(lane & 31);             // row/col 0..31
    float g2h = g2 + 32.0f;                    // row/col 32..63

    if (s0 < NN) {                             // idle tail streams exit fast
        for (int grp = 0; grp < GRPS; ++grp) {
            int nb = s0 + grp * 16 + half8;
            float4 bb[8];
            #pragma unroll
            for (int j = 0; j < 8; ++j) {
                int nt = nb + j;
                bb[j] = bb_b[nt < NN ? nt : NN - 1];
            }
            bf16x8 A0, A1, B0, B1;
            #pragma unroll
            for (int j = 0; j < 8; ++j) {
                float okf = (nb + j < NN) ? 1.0f : 0.0f;
                float4 q = bb[j];
                float inv = fast_rcp(fmaxf((q.y - q.x + 1.0f) * (q.w - q.z + 1.0f), 1.0f)) * okf;
                // y-profile (A = Y^T): rows g2 / g2h
                float a0 = sigmoidf(KSOFT * (g2  - q.z + 0.5f)) * sigmoidf(KSOFT * (q.w - g2  + 0.5f)) * inv;
                float a1 = sigmoidf(KSOFT * (g2h - q.z + 0.5f)) * sigmoidf(KSOFT * (q.w - g2h + 0.5f)) * inv;
                // x-profile (B = X): cols g2 / g2h
                float b0 = sigmoidf(KSOFT * (g2  - q.x + 0.5f)) * sigmoidf(KSOFT * (q.y - g2  + 0.5f)) * okf;
                float b1 = sigmoidf(KSOFT * (g2h - q.x + 0.5f)) * sigmoidf(KSOFT * (q.y - g2h + 0.5f)) * okf;
                A0[j] = f2bf(a0); A1[j] = f2bf(a1);
                B0[j] = f2bf(b0); B1[j] = f2bf(b1);
            }
            acc00 = __builtin_amdgcn_mfma_f32_32x32x16_bf16(A0, B0, acc00, 0, 0, 0);
            acc01 = __builtin_amdgcn_mfma_f32_32x32x16_bf16(A0, B1, acc01, 0, 0, 0);
            acc10 = __builtin_amdgcn_mfma_f32_32x32x16_bf16(A1, B0, acc10, 0, 0, 0);
            acc11 = __builtin_amdgcn_mfma_f32_32x32x16_bf16(A1, B1, acc11, 0, 0, 0);
        }
    }

    // C/D layout: col=lane&31, row=(r&3)+8*(r>>2)+4*(lane>>5)  (LDS atomics: intra-block)
    int col = lane & 31, rq = lane >> 5;
    #pragma unroll
    for (int r = 0; r < 16; ++r) {
        int row = (r & 3) + 8 * (r >> 2) + 4 * rq;
        atomicAdd(&tile[row * 65 + col],             acc00[r]);
        atomicAdd(&tile[row * 65 + col + 32],        acc01[r]);
        atomicAdd(&tile[(row + 32) * 65 + col],      acc10[r]);
        atomicAdd(&tile[(row + 32) * 65 + col + 32], acc11[r]);
    }
    __syncthreads();
    float* slab = slabs + ((size_t)b * BPB + sub) * 4096;
    for (int k = tid; k < 4096; k += 256)
        slab[k] = tile[(k >> 6) * 65 + (k & 63)];
}

// Sum BPB slabs -> rudy. XCD-pinned to the pair that wrote the slabs (L2 hits).
__global__ void __launch_bounds__(256)
rudy_reduce_kernel(const float* __restrict__ slabs, float* __restrict__ rudy) {
    int blk = blockIdx.x;                       // 64
    int xcd = blk & 7;
    int b = xcd >> 1;
    int sub = ((blk >> 3) << 1) | (xcd & 1);    // 0..15
    int c = sub * 256 + threadIdx.x;            // cell 0..4095
    const float* base = slabs + (size_t)b * BPB * 4096 + c;
    float a0 = 0.f, a1 = 0.f, a2 = 0.f, a3 = 0.f;
    #pragma unroll 4
    for (int s = 0; s < BPB; s += 4) {
        a0 += base[(size_t)(s + 0) * 4096];
        a1 += base[(size_t)(s + 1) * 4096];
        a2 += base[(size_t)(s + 2) * 4096];
        a3 += base[(size_t)(s + 3) * 4096];
    }
    rudy[b * 4096 + c] = (a0 + a1) + (a2 + a3);
}

__global__ void conv_penalty_kernel(const float* __restrict__ rudy,
                                    float* __restrict__ pen) {
    int blk = blockIdx.x;
    int b = blk >> 4, chunk = blk & 15;
    int r0 = chunk * 4;
    __shared__ float t2[10][64];
    int tid = threadIdx.x;
    for (int k = tid; k < 640; k += 256) {
        int r = k >> 6, c = k & 63, row = r0 - 3 + r;
        t2[r][c] = (row >= 0 && row < 64) ? rudy[b * 4096 + row * 64 + c] : 0.f;
    }
    __syncthreads();
    float g1[7];
    #pragma unroll
    for (int i = 0; i < 7; ++i) { float t = (float)(i - 3); g1[i] = __expf(-t * t / 4.5f); }
    float s1 = g1[0] + g1[1] + g1[2] + g1[3] + g1[4] + g1[5] + g1[6];
    float inv = fast_rcp(s1 * s1);
    int i = tid >> 6, j = tid & 63;
    float acc = 0.f;
    #pragma unroll
    for (int di = -3; di <= 3; ++di) {
        #pragma unroll
        for (int dj = -3; dj <= 3; ++dj) {
            int jj = j + dj;
            float val = (jj >= 0 && jj < 64) ? t2[i + 3 + di][jj] : 0.f;
            acc += g1[di + 3] * g1[dj + 3] * val;
        }
    }
    acc *= inv;
    float ov = acc - THRESH;
    float p = ov > 0.f ? ov * ov : 0.f;
    DPP5(p, op_add, 0.0f);
    float tot = rdlane(p, 31) + rdlane(p, 63);
    if ((tid & 63) == 0) atomicAdd(&pen[b], tot);
}

__global__ void finalize_kernel(const float* __restrict__ hpwl,
                                const float* __restrict__ pen,
                                float* __restrict__ out) {
    int i = threadIdx.x;
    if (i < B) out[i] = W_WL * hpwl[i] + W_CONG * pen[i];
}

} // namespace

extern "C" void kernel_launch(void* const* d_in, const int* in_sizes, int n_in,
                              void* d_out, int out_size, void* d_ws, size_t ws_size,
                              hipStream_t stream) {
    const float* positions    = (const float*)d_in[0];
    const int*   net_to_pin   = (const int*)d_in[1];
    const int*   pin_to_macro = (const int*)d_in[2];
    const float* pin_offsets  = (const float*)d_in[3];
    const float* rot_onehot   = (const float*)d_in[4];
    const float* net_weights  = (const float*)d_in[5];
    float* out = (float*)d_out;

    // ws: pin_pos | rudy | hpwl | pen | mac | bbox | n2pT | slabs  (~32 MB)
    float*  pin_pos = (float*)d_ws;
    float*  rudy    = pin_pos + (size_t)B * P * 2;
    float*  hpwl    = rudy + (size_t)B * 64 * 64;
    float*  pen     = hpwl + B;
    float4* mac     = (float4*)(pen + B);
    float4* bboxb   = mac + (size_t)B * V;
    int*    n2pT    = (int*)(bboxb + (size_t)B * NN);
    float*  slabs   = (float*)(n2pT + (size_t)NN * MP);

    zero_ws_kernel<<<1, 64, 0, stream>>>(hpwl, 2 * B);
    macro_prep_kernel<<<(B * V + 255) / 256, 256, 0, stream>>>(positions, rot_onehot, mac);
    pin_pos_kernel<<<(B * P + 255) / 256, 256, 0, stream>>>(mac, pin_to_macro, pin_offsets, pin_pos);
    transpose_n2p_kernel<<<(NN * MP + 255) / 256, 256, 0, stream>>>(net_to_pin, n2pT);
    bbox_kernel<<<A_GRID, 256, 0, stream>>>(pin_pos, n2pT, net_weights, bboxb, hpwl);
    rudy_kernel<<<NET_GRID, 256, 0, stream>>>(bboxb, slabs);
    rudy_reduce_kernel<<<64, 256, 0, stream>>>(slabs, rudy);
    conv_penalty_kernel<<<64, 256, 0, stream>>>(rudy, pen);
    finalize_kernel<<<1, 64, 0, stream>>>(hpwl, pen, out);
}